// Round 1
// baseline (1405.346 us; speedup 1.0000x reference)
//
#include <hip/hip_runtime.h>
#include <hip/hip_bf16.h>

#define A_N 21
#define D_N 128
#define H_N 256
#define V_N 32000
#define N_TOK 4096
#define EPS 1e-5f

typedef short bf16x8 __attribute__((ext_vector_type(8)));
typedef float floatx4 __attribute__((ext_vector_type(4)));

__device__ inline short f2bf(float f) {
    unsigned u = __builtin_bit_cast(unsigned, f);
    unsigned r = u + 0x7fffu + ((u >> 16) & 1u);
    return (short)(r >> 16);
}

// ---------------------------------------------------------------------------
// Kernel 1: transpose + bf16-convert Wout [128][32000] -> WoutT [32000][128]
// ---------------------------------------------------------------------------
__global__ __launch_bounds__(256) void transpose_wout(
    const float* __restrict__ Wout, short* __restrict__ WoutT)
{
    __shared__ float tile[32][33];
    int n0 = blockIdx.x * 32;   // 1000 blocks in x
    int d0 = blockIdx.y * 32;   // 4 blocks in y
    int c = threadIdx.x & 31;
    int r = threadIdx.x >> 5;   // 0..7
#pragma unroll
    for (int rr = 0; rr < 4; ++rr) {
        int d = d0 + r + rr * 8;
        tile[r + rr * 8][c] = Wout[(long)d * V_N + n0 + c];
    }
    __syncthreads();
#pragma unroll
    for (int rr = 0; rr < 4; ++rr) {
        int n = n0 + r + rr * 8;
        WoutT[(long)n * 128 + d0 + c] = f2bf(tile[c][r + rr * 8]);
    }
}

// ---------------------------------------------------------------------------
// Kernel 2: per-token agent-ensemble MLP -> hidden [4096][128] bf16
// One block = 16 tokens, 256 threads. fp32 VALU math.
// ---------------------------------------------------------------------------
__global__ __launch_bounds__(256) void stage1(
    const int* __restrict__ x, const float* __restrict__ emb,
    const float* __restrict__ g1, const float* __restrict__ b1ln,
    const float* __restrict__ W1, const float* __restrict__ bfc1,
    const float* __restrict__ g2, const float* __restrict__ b2ln,
    const float* __restrict__ W2, const float* __restrict__ bfc2,
    short* __restrict__ hiddenBf)
{
    // stride-20 rows: 80B (16B-aligned for float4), spreads banks for d-varying ops
    __shared__ __attribute__((aligned(16))) float flatL[128][20];
    __shared__ __attribute__((aligned(16))) float xhatL[128][20];
    __shared__ __attribute__((aligned(16))) float xnL[128][20];     // aliased as pbuf in fc2
    __shared__ __attribute__((aligned(16))) float accsum[128][20];
    __shared__ __attribute__((aligned(16))) float hbuf[256][20];
    __shared__ float redS[16][17], redS2[16][17];
    __shared__ float muL[16], rsL[16], mu2L[16], rs2L[16];

    int tid = threadIdx.x;
    int t0 = blockIdx.x * 16;

    // load flat (coalesced per token) + zero accsum
    for (int idx = tid; idx < 2048; idx += 256) {
        int k = idx >> 7, d = idx & 127;
        flatL[d][k] = emb[(long)x[t0 + k] * 128 + d];
    }
    for (int idx = tid; idx < 2048; idx += 256) {
        int d = idx >> 4, k = idx & 15;
        accsum[d][k] = 0.f;
    }
    __syncthreads();

    // LN1 stats (16 threads, one token each)
    if (tid < 16) {
        float s = 0.f, s2 = 0.f;
        for (int d = 0; d < 128; ++d) { float v = flatL[d][tid]; s += v; s2 += v * v; }
        float mu = s * (1.f / 128.f);
        float var = s2 * (1.f / 128.f) - mu * mu;
        muL[tid] = mu;
        rsL[tid] = rsqrtf(var + EPS);
    }
    __syncthreads();
    for (int idx = tid; idx < 2048; idx += 256) {
        int d = idx >> 4, k = idx & 15;
        xhatL[d][k] = (flatL[d][k] - muL[k]) * rsL[k];
    }
    __syncthreads();

    float (*pbuf)[20] = xnL;  // reuse: xn dead once fc1 finishes

    for (int a = 0; a < A_N; ++a) {
        // per-agent affine on xhat
        for (int idx = tid; idx < 2048; idx += 256) {
            int d = idx >> 4, k = idx & 15;
            xnL[d][k] = xhatL[d][k] * g1[a * 128 + d] + b1ln[a * 128 + d];
        }
        __syncthreads();

        // fc1: h[tid][k] = bfc1 + sum_d xn[d][k] * W1[a][d][tid]
        float h[16];
        float bias1 = bfc1[a * 256 + tid];
#pragma unroll
        for (int k = 0; k < 16; ++k) h[k] = bias1;
        for (int d = 0; d < 128; ++d) {
            float w = W1[((long)a * 128 + d) * 256 + tid];
            const float4* xr = (const float4*)(&xnL[d][0]);
            float4 xv0 = xr[0], xv1 = xr[1], xv2 = xr[2], xv3 = xr[3];
            float xf[16] = {xv0.x, xv0.y, xv0.z, xv0.w, xv1.x, xv1.y, xv1.z, xv1.w,
                            xv2.x, xv2.y, xv2.z, xv2.w, xv3.x, xv3.y, xv3.z, xv3.w};
#pragma unroll
            for (int k = 0; k < 16; ++k) h[k] = fmaf(xf[k], w, h[k]);
        }
        // exact GELU
#pragma unroll
        for (int k = 0; k < 16; ++k)
            h[k] = 0.5f * h[k] * (1.f + erff(h[k] * 0.70710678118654752f));

        // stage h to LDS for LN2 reduction + fc2 broadcast
#pragma unroll
        for (int k = 0; k < 16; ++k) hbuf[tid][k] = h[k];
        __syncthreads();

        // LN2 stats: 16 partials per token
        {
            int k = tid & 15, j = tid >> 4;
            float s = 0.f, s2 = 0.f;
            for (int t = j * 16; t < j * 16 + 16; ++t) {
                float v = hbuf[t][k]; s += v; s2 += v * v;
            }
            redS[k][j] = s; redS2[k][j] = s2;
        }
        __syncthreads();
        if (tid < 16) {
            float s = 0.f, s2 = 0.f;
            for (int j = 0; j < 16; ++j) { s += redS[tid][j]; s2 += redS2[tid][j]; }
            float mu = s * (1.f / 256.f);
            float var = s2 * (1.f / 256.f) - mu * mu;
            mu2L[tid] = mu;
            rs2L[tid] = rsqrtf(var + EPS);
        }
        __syncthreads();

        // hn into hbuf
        {
            float g2v = g2[a * 256 + tid], b2v = b2ln[a * 256 + tid];
#pragma unroll
            for (int k = 0; k < 16; ++k)
                hbuf[tid][k] = (h[k] - mu2L[k]) * rs2L[k] * g2v + b2v;
        }
        __syncthreads();

        // fc2: out[d][k] = sum_t hn[t][k] * W2[a][t][d]; split t over two halves
        {
            int d = tid & 127, half = tid >> 7;
            float acc2[16];
#pragma unroll
            for (int k = 0; k < 16; ++k) acc2[k] = 0.f;
            for (int tt = 0; tt < 128; ++tt) {
                int t = half * 128 + tt;
                float w = W2[((long)a * 256 + t) * 128 + d];
                const float4* hr = (const float4*)(&hbuf[t][0]);
                float4 hv0 = hr[0], hv1 = hr[1], hv2 = hr[2], hv3 = hr[3];
                float hf[16] = {hv0.x, hv0.y, hv0.z, hv0.w, hv1.x, hv1.y, hv1.z, hv1.w,
                                hv2.x, hv2.y, hv2.z, hv2.w, hv3.x, hv3.y, hv3.z, hv3.w};
#pragma unroll
                for (int k = 0; k < 16; ++k) acc2[k] = fmaf(hf[k], w, acc2[k]);
            }
            if (half) {
#pragma unroll
                for (int k = 0; k < 16; ++k) pbuf[d][k] = acc2[k];
            }
            __syncthreads();
            if (!half) {
                float bb = bfc2[a * 128 + d];
#pragma unroll
                for (int k = 0; k < 16; ++k)
                    accsum[d][k] += acc2[k] + pbuf[d][k] + bb;
            }
            __syncthreads();
        }
    }

    // hidden = 2*flat + accsum/21 ; write bf16 (coalesced per token)
    for (int idx = tid; idx < 2048; idx += 256) {
        int k = idx >> 7, d = idx & 127;
        float hv = 2.f * flatL[d][k] + accsum[d][k] * (1.f / 21.f);
        hiddenBf[(long)(t0 + k) * 128 + d] = f2bf(hv);
    }
}

// ---------------------------------------------------------------------------
// Kernel 3: logits = hidden @ WoutT^T + bout via bf16 MFMA
// block = 4 waves; block tile 64(M) x 256(N); wave tile 64x64
// ---------------------------------------------------------------------------
__global__ __launch_bounds__(256) void stage2(
    const short* __restrict__ Abf,   // hidden bf16 [4096][128]
    const short* __restrict__ Bbf,   // WoutT bf16 [32000][128]
    const float* __restrict__ bout,
    float* __restrict__ out)         // [4096][32000]
{
    int wid = threadIdx.x >> 6;
    int lane = threadIdx.x & 63;
    int m0 = blockIdx.y * 64;                 // grid.y = 64
    int n0 = blockIdx.x * 256 + wid * 64;     // grid.x = 125
    int lr = lane & 15;
    int lk = (lane >> 4) * 8;

    floatx4 acc[4][4] = {};
    const short* Ap = Abf + (long)(m0 + lr) * 128 + lk;
    const short* Bp = Bbf + (long)(n0 + lr) * 128 + lk;

#pragma unroll
    for (int kk = 0; kk < 4; ++kk) {
        bf16x8 afr[4], bfr[4];
#pragma unroll
        for (int t = 0; t < 4; ++t) {
            afr[t] = *(const bf16x8*)(Ap + t * 16 * 128 + kk * 32);
            bfr[t] = *(const bf16x8*)(Bp + t * 16 * 128 + kk * 32);
        }
#pragma unroll
        for (int mt = 0; mt < 4; ++mt)
#pragma unroll
            for (int nt = 0; nt < 4; ++nt)
                acc[mt][nt] = __builtin_amdgcn_mfma_f32_16x16x32_bf16(
                    afr[mt], bfr[nt], acc[mt][nt], 0, 0, 0);
    }

    int row_base = m0 + (lane >> 4) * 4;
#pragma unroll
    for (int nt = 0; nt < 4; ++nt) {
        int col = n0 + nt * 16 + lr;
        float bo = bout[col];
#pragma unroll
        for (int mt = 0; mt < 4; ++mt) {
#pragma unroll
            for (int r = 0; r < 4; ++r) {
                int row = row_base + mt * 16 + r;
                out[(long)row * V_N + col] = acc[mt][nt][r] + bo;
            }
        }
    }
}

// ---------------------------------------------------------------------------
extern "C" void kernel_launch(void* const* d_in, const int* in_sizes, int n_in,
                              void* d_out, int out_size, void* d_ws, size_t ws_size,
                              hipStream_t stream) {
    const int*   x    = (const int*)d_in[0];
    const float* emb  = (const float*)d_in[1];
    const float* Wout = (const float*)d_in[2];
    const float* bout = (const float*)d_in[3];
    const float* g1   = (const float*)d_in[4];
    const float* b1   = (const float*)d_in[5];
    const float* W1   = (const float*)d_in[6];
    const float* bfc1 = (const float*)d_in[7];
    const float* g2   = (const float*)d_in[8];
    const float* b2   = (const float*)d_in[9];
    const float* W2   = (const float*)d_in[10];
    const float* bfc2 = (const float*)d_in[11];
    float* out = (float*)d_out;

    short* hiddenBf = (short*)d_ws;                                  // 1 MB
    short* WoutT    = (short*)((char*)d_ws + (size_t)N_TOK * 128 * 2);  // 8.2 MB

    transpose_wout<<<dim3(1000, 4), dim3(256), 0, stream>>>(Wout, WoutT);
    stage1<<<dim3(256), dim3(256), 0, stream>>>(x, emb, g1, b1, W1, bfc1,
                                                g2, b2, W2, bfc2, hiddenBf);
    stage2<<<dim3(125, 64), dim3(256), 0, stream>>>(hiddenBf, WoutT, bout, out);
}